// Round 5
// baseline (3025.406 us; speedup 1.0000x reference)
//
#include <hip/hip_runtime.h>
#include <cstddef>

// ---------------------------------------------------------------------------
// RelGraphConv GNN, 10 layers. Round 13: counted-vmcnt 3-deep DMA pipeline.
//   R12 confirmed the in-flight-bytes theory (1.06 -> 3.3 TB/s). Remaining
//   gap to 6.3 TB/s: (a) per-step __syncthreads drains vmcnt(0) -> DMA queue
//   collapses every 16 KB; (b) grid order (m fastest) re-fetches x 2.4x from
//   HBM after Z-stream evicts it from L3.
//   Fix (a): T4 counted vmcnt — 3 LDS buffers, raw s_barrier (no drain),
//   s_waitcnt vmcnt(4*(depth-1)) so step k+2 DMAs stay in flight across
//   barriers. Each wave issues exactly 4 DMAs/stage -> counts are exact.
//   Fix (b): grid swap, column tiles fastest -> x-stripe L3-temporal reuse.
// Z buffer (128 MB) aliases mid (dead during Z/segsum); ws ~214 MB.
// N=100000, E=600000, F=64, H=128, R=8.
// ---------------------------------------------------------------------------

#define HID 128
#define NREL 8
#define NL 10

typedef __attribute__((ext_vector_type(8))) __bf16 bf16x8;
typedef __attribute__((ext_vector_type(4))) float f32x4;

__device__ __forceinline__ float fast_tanh(float x) {
  float cx = fminf(fmaxf(x, -10.f), 10.f);
  float z = exp2f(cx * 2.8853900817779268f);
  return (z - 1.f) * __builtin_amdgcn_rcpf(z + 1.f);
}

template <int N>
__device__ __forceinline__ void s_waitcnt_vm() {
  asm volatile("s_waitcnt vmcnt(%0)" ::"n"(N) : "memory");
}

// --- batched transpose + f32->bf16: tile z: W[zi][K][Nc] -> Wt[zo][Nc][K] ---
__global__ __launch_bounds__(256) void k_transpose(const float* __restrict__ W,
                                                   __bf16* __restrict__ Wt,
                                                   int K, int Nc,
                                                   int inDiv, int inScale, int inOff,
                                                   int outDiv, int outScale, int outOff) {
  __shared__ float t[32][33];
  int z = blockIdx.z;
  int zi = (z / inDiv) * inScale + (z % inDiv) + inOff;
  int zo = (z / outDiv) * outScale + (z % outDiv) + outOff;
  const float* Wz = W + (size_t)zi * K * Nc;
  __bf16* Wtz = Wt + (size_t)zo * K * Nc;
  int n0 = blockIdx.x * 32, k0 = blockIdx.y * 32;
#pragma unroll
  for (int i = 0; i < 4; i++) {
    int k = k0 + threadIdx.y + i * 8;
    int n = n0 + threadIdx.x;
    t[threadIdx.y + i * 8][threadIdx.x] = Wz[(size_t)k * Nc + n];
  }
  __syncthreads();
#pragma unroll
  for (int i = 0; i < 4; i++) {
    int n = n0 + threadIdx.y + i * 8;
    int k = k0 + threadIdx.x;
    Wtz[(size_t)n * K + k] = (__bf16)t[threadIdx.x][threadIdx.y + i * 8];
  }
}

// --- f32 -> bf16 elementwise (n4 = count/4) ---
__global__ __launch_bounds__(256) void k_cvt(const float* __restrict__ x,
                                             __bf16* __restrict__ y, int n4) {
  int i = blockIdx.x * 256 + threadIdx.x;
  if (i < n4) {
    float4 f = ((const float4*)x)[i];
    __bf16 o[4] = {(__bf16)f.x, (__bf16)f.y, (__bf16)f.z, (__bf16)f.w};
    *(uint2*)(y + (size_t)i * 4) = *(uint2*)o;
  }
}

// ===================== dst-CSR build (once per launch) ======================
__global__ __launch_bounds__(256) void k_zero(int* __restrict__ p, int n) {
  for (int i = blockIdx.x * 256 + threadIdx.x; i < n; i += gridDim.x * 256) p[i] = 0;
}

__global__ __launch_bounds__(256) void k_hist_row(const int* __restrict__ dst,
                                                  int E, int* __restrict__ rowCnt) {
  int e = blockIdx.x * 256 + threadIdx.x;
  if (e < E) atomicAdd(&rowCnt[dst[e]], 1);
}

// --- hierarchical prefix scan over rowCnt[0..nb) ---------------------------
__global__ __launch_bounds__(256) void k_scan_part(const int* __restrict__ rowCnt,
                                                   int nb, int* __restrict__ thrPre,
                                                   int* __restrict__ blkSum) {
  __shared__ int sdata[256];
  int tid = threadIdx.x;
  int gtid = blockIdx.x * 256 + tid;
  int tot = gridDim.x * 256;
  int chunk = (nb + tot - 1) / tot;
  int lo = gtid * chunk, hi = min(nb, lo + chunk);
  int s = 0;
  for (int i = lo; i < hi; i++) s += rowCnt[i];
  sdata[tid] = s;
  __syncthreads();
#pragma unroll
  for (int off = 1; off < 256; off <<= 1) {
    int t = (tid >= off) ? sdata[tid - off] : 0;
    __syncthreads();
    sdata[tid] += t;
    __syncthreads();
  }
  thrPre[gtid] = sdata[tid] - s;
  if (tid == 255) blkSum[blockIdx.x] = sdata[255];
}

__global__ __launch_bounds__(256) void k_scan_mid(const int* __restrict__ blkSum,
                                                  int nblk, int nb,
                                                  int* __restrict__ blkOff,
                                                  int* __restrict__ rowStart) {
  __shared__ int part[256];
  int tid = threadIdx.x;
  part[tid] = (tid < nblk) ? blkSum[tid] : 0;
  __syncthreads();
  if (tid == 0) {
    int a = 0;
    for (int i = 0; i < nblk; i++) { int v = part[i]; part[i] = a; a += v; }
    rowStart[nb] = a;
  }
  __syncthreads();
  if (tid < nblk) blkOff[tid] = part[tid];
}

__global__ __launch_bounds__(256) void k_scan_fin(const int* __restrict__ rowCnt,
                                                  int nb,
                                                  const int* __restrict__ thrPre,
                                                  const int* __restrict__ blkOff,
                                                  int* __restrict__ rowStart,
                                                  int* __restrict__ rowCur) {
  int tid = threadIdx.x;
  int gtid = blockIdx.x * 256 + tid;
  int tot = gridDim.x * 256;
  int chunk = (nb + tot - 1) / tot;
  int lo = gtid * chunk, hi = min(nb, lo + chunk);
  int run = blkOff[blockIdx.x] + thrPre[gtid];
  for (int i = lo; i < hi; i++) {
    rowStart[i] = run;
    rowCur[i] = run;
    run += rowCnt[i];
  }
}

// pack: src (17 bits) | etype << 17
__global__ __launch_bounds__(256) void k_place_row(const int* __restrict__ et,
                                                   const int* __restrict__ src,
                                                   const int* __restrict__ dst,
                                                   int* __restrict__ rowCur,
                                                   int* __restrict__ epk, int E) {
  int e = blockIdx.x * 256 + threadIdx.x;
  if (e < E) {
    int p = atomicAdd(&rowCur[dst[e]], 1);
    epk[p] = src[e] | (et[e] << 17);
  }
}

// ========================= CSR segment-sum kernel ===========================
__global__ __launch_bounds__(256) void seg_sum(
    const __bf16* __restrict__ Z, const int* __restrict__ rowStart,
    const int* __restrict__ epk, const float* __restrict__ b_rel_l,
    __bf16* __restrict__ msgb, int N, int relBase, int zW, int selfCol) {
  int t16 = threadIdx.x & 15;
  int d = blockIdx.x * 16 + (threadIdx.x >> 4);
  if (d >= N) return;

  float acc[8];
  if (selfCol >= 0) {
    bf16x8 sv = *(const bf16x8*)(Z + (size_t)d * zW + selfCol + t16 * 8);
#pragma unroll
    for (int z = 0; z < 8; z++) acc[z] = (float)sv[z] + b_rel_l[t16 * 8 + z];
  } else {
    bf16x8 mv = *(const bf16x8*)(msgb + (size_t)d * HID + t16 * 8);
#pragma unroll
    for (int z = 0; z < 8; z++) acc[z] = (float)mv[z];
  }

  int lo = rowStart[d], hi = rowStart[d + 1];
  for (int e = lo; e < hi; e++) {
    int p = epk[e];
    int rr = (p >> 17) - relBase;
    if ((unsigned)rr < 4u) {
      bf16x8 v = *(const bf16x8*)(Z + (size_t)(p & 0x1FFFF) * zW + rr * HID + t16 * 8);
#pragma unroll
      for (int z = 0; z < 8; z++) acc[z] += (float)v[z];
    }
  }

  bf16x8 o;
#pragma unroll
  for (int z = 0; z < 8; z++) o[z] = (__bf16)acc[z];
  *(bf16x8*)(msgb + (size_t)d * HID + t16 * 8) = o;
}

// ---------------------------------------------------------------------------
// DMA-staged bf16 MFMA GEMM, counted-vmcnt 3-deep pipeline.
//   C = act(concat(A0,A1) @ B + bias). 128x128 C-tile, 256 threads.
//   BK=32 staged via global_load_lds into D=3 rotating buffers.
//   Per iter: raw s_barrier (buf-reuse safety, no drain) -> stage(k+D-1) ->
//   s_waitcnt vmcnt(4*inflight) -> raw s_barrier (tile ready) -> MFMA.
//   Each wave issues exactly 4 DMA insts per stage -> vmcnt counts exact.
//   grid: blockIdx.x = column tile (fastest -> x-stripe L3 reuse),
//         blockIdx.y = m tile.
// ---------------------------------------------------------------------------
template <int K, int K0, int MINW>
__global__ __launch_bounds__(256, MINW) void gemm_lds(
    const __bf16* __restrict__ A0, const __bf16* __restrict__ A1,
    const __bf16* __restrict__ Bt, const float* __restrict__ bias,
    __bf16* __restrict__ Cb, float* __restrict__ Cf,
    int M, int Nc, int act) {
  constexpr int NS = K / 32;               // K-steps
  constexpr int NS0 = K0 / 32;             // steps sourced from A0
  constexpr int K1 = (K - K0) > 0 ? (K - K0) : 1;
  constexpr int D = (NS < 3) ? NS : 3;     // pipeline depth (buffers)
  __shared__ __bf16 As[D][128][32];
  __shared__ __bf16 Bs[D][128][32];

  const int tid = threadIdx.x;
  const int m0 = blockIdx.y * 128;
  const int bn0 = blockIdx.x * 128;
  const int w = tid >> 6;
  const int lane = tid & 63;

  // DMA chunk geometry: chunk c (16B) -> row c>>2, 16B-slot c&3.
  const int cA = w * 128 + lane;
  const int r0 = cA >> 2, s0 = cA & 3;
  const int r1 = (cA + 64) >> 2, s1 = (cA + 64) & 3;

  auto stage_step = [&](int b, int ks) {
    // B tile (rows = output cols, stride K)
    {
      const __bf16* g0 = Bt + (size_t)(bn0 + r0) * K + ks * 32 + s0 * 8;
      __builtin_amdgcn_global_load_lds(
          (const __attribute__((address_space(1))) void*)g0,
          (__attribute__((address_space(3))) void*)(&Bs[b][0][0] + (w * 2 + 0) * 512),
          16, 0, 0);
      const __bf16* g1 = Bt + (size_t)(bn0 + r1) * K + ks * 32 + s1 * 8;
      __builtin_amdgcn_global_load_lds(
          (const __attribute__((address_space(1))) void*)g1,
          (__attribute__((address_space(3))) void*)(&Bs[b][0][0] + (w * 2 + 1) * 512),
          16, 0, 0);
    }
    // A tile: concat segment select (wave-uniform per step)
    if (ks < NS0) {
      const __bf16* g0 = A0 + (size_t)(m0 + r0) * K0 + ks * 32 + s0 * 8;
      __builtin_amdgcn_global_load_lds(
          (const __attribute__((address_space(1))) void*)g0,
          (__attribute__((address_space(3))) void*)(&As[b][0][0] + (w * 2 + 0) * 512),
          16, 0, 0);
      const __bf16* g1 = A0 + (size_t)(m0 + r1) * K0 + ks * 32 + s1 * 8;
      __builtin_amdgcn_global_load_lds(
          (const __attribute__((address_space(1))) void*)g1,
          (__attribute__((address_space(3))) void*)(&As[b][0][0] + (w * 2 + 1) * 512),
          16, 0, 0);
    } else {
      const __bf16* g0 = A1 + (size_t)(m0 + r0) * K1 + (ks - NS0) * 32 + s0 * 8;
      __builtin_amdgcn_global_load_lds(
          (const __attribute__((address_space(1))) void*)g0,
          (__attribute__((address_space(3))) void*)(&As[b][0][0] + (w * 2 + 0) * 512),
          16, 0, 0);
      const __bf16* g1 = A1 + (size_t)(m0 + r1) * K1 + (ks - NS0) * 32 + s1 * 8;
      __builtin_amdgcn_global_load_lds(
          (const __attribute__((address_space(1))) void*)g1,
          (__attribute__((address_space(3))) void*)(&As[b][0][0] + (w * 2 + 1) * 512),
          16, 0, 0);
    }
  };

  const int ml = lane & 15, q = lane >> 4;
  const int wr = (w >> 1) * 64, wc = (w & 1) * 64;

  f32x4 acc[4][4];
#pragma unroll
  for (int i = 0; i < 4; i++)
#pragma unroll
    for (int j = 0; j < 4; j++)
#pragma unroll
      for (int r = 0; r < 4; r++) acc[i][j][r] = 0.f;

  // prologue: stage steps 0..D-2  (4*(D-1) DMAs in flight per wave)
#pragma unroll
  for (int p = 0; p < D - 1; p++) stage_step(p, p);

#pragma unroll
  for (int ks = 0; ks < NS; ks++) {
    // all waves finished reading buf[(ks-1)%D] == buf[(ks+D-1)%D]
    __builtin_amdgcn_s_barrier();
    if (ks + D - 1 < NS) stage_step((ks + D - 1) % D, ks + D - 1);
    // wait own step-ks DMAs (leave later steps in flight), then all-waves sync
    {
      const int rem = NS - ks - 1;
      const int cnt = 4 * (rem < D - 1 ? rem : D - 1);
      if (cnt == 8) s_waitcnt_vm<8>();
      else if (cnt == 4) s_waitcnt_vm<4>();
      else s_waitcnt_vm<0>();
    }
    __builtin_amdgcn_sched_barrier(0);
    __builtin_amdgcn_s_barrier();
    __builtin_amdgcn_sched_barrier(0);

    const int cur = ks % D;
    bf16x8 af[4], bfr[4];
#pragma unroll
    for (int i = 0; i < 4; i++)
      af[i] = *(const bf16x8*)(&As[cur][wr + i * 16 + ml][q * 8]);
#pragma unroll
    for (int j = 0; j < 4; j++)
      bfr[j] = *(const bf16x8*)(&Bs[cur][wc + j * 16 + ml][q * 8]);
#pragma unroll
    for (int i = 0; i < 4; i++)
#pragma unroll
      for (int j = 0; j < 4; j++)
        acc[i][j] = __builtin_amdgcn_mfma_f32_16x16x32_bf16(af[i], bfr[j],
                                                            acc[i][j], 0, 0, 0);
  }

  // --- epilogue ---
#pragma unroll
  for (int i = 0; i < 4; i++) {
#pragma unroll
    for (int r = 0; r < 4; r++) {
      int grow = m0 + wr + i * 16 + q * 4 + r;
      if (grow >= M) continue;
#pragma unroll
      for (int j = 0; j < 4; j++) {
        int col = bn0 + wc + j * 16 + ml;
        float v = acc[i][j][r];
        if (bias) v += bias[col];
        if (act) v = fast_tanh(v);
        if (Cb) Cb[(size_t)grow * Nc + col] = (__bf16)v;
        if (Cf) Cf[(size_t)grow * Nc + col] = v;
      }
    }
  }
}

extern "C" void kernel_launch(void* const* d_in, const int* in_sizes, int n_in,
                              void* d_out, int out_size, void* d_ws, size_t ws_size,
                              hipStream_t stream) {
  const float* feats  = (const float*)d_in[0];
  const int*   src    = (const int*)d_in[1];
  const int*   dst    = (const int*)d_in[2];
  const int*   etype  = (const int*)d_in[3];
  const float* W_in   = (const float*)d_in[4];
  const float* b_in   = (const float*)d_in[5];
  const float* W_rel  = (const float*)d_in[6];
  const float* W_loop = (const float*)d_in[7];
  const float* b_rel  = (const float*)d_in[8];
  const float* W_u1   = (const float*)d_in[9];
  const float* b_u1   = (const float*)d_in[10];
  const float* W_u2   = (const float*)d_in[11];
  const float* b_u2   = (const float*)d_in[12];

  const int E = in_sizes[1];
  const int N = in_sizes[0] / 64;
  const int TS = HID * HID;

  // --- workspace layout (~214 MB) ---
  __bf16* xb0  = (__bf16*)d_ws;                       // N*128
  __bf16* xb1  = xb0 + (size_t)N * HID;               // N*128
  __bf16* msgb = xb1 + (size_t)N * HID;               // N*128
  __bf16* U    = msgb + (size_t)N * HID;              // N*640 (Z | mid | featsb)
  __bf16* Z    = U;
  __bf16* mid  = U;
  __bf16* featsb = U;
  __bf16* wt_in = U + (size_t)N * 640;                // [128][64]
  __bf16* wt_z0 = wt_in + 128 * 64;                   // [10][5][128][128]
  __bf16* wt_z1 = wt_z0 + (size_t)10 * 5 * TS;        // [10][4][128][128]
  __bf16* wt_u1 = wt_z1 + (size_t)10 * 4 * TS;        // [10][256][256]
  __bf16* wt_u2 = wt_u1 + (size_t)10 * 256 * 256;     // [10][128][384]
  int* rowCnt   = (int*)(wt_u2 + (size_t)10 * 128 * 384); // N
  int* rowStart = rowCnt + N;                         // N+1
  int* rowCur   = rowStart + N + 1;                   // N
  int* epk      = rowCur + N;                         // E
  int* thrPre   = epk + E;                            // 256*256
  int* blkSum   = thrPre + 256 * 256;                 // 256
  int* blkOff   = blkSum + 256;                       // 256

  // --- weight transpose+convert ---
  k_transpose<<<dim3(4, 2, 1), dim3(32, 8), 0, stream>>>(W_in, wt_in, 64, 128,
                                                         1, 1, 0, 1, 1, 0);
  k_transpose<<<dim3(4, 4, 40), dim3(32, 8), 0, stream>>>(W_rel, wt_z0, 128, 128,
                                                          4, 8, 0, 4, 5, 0);
  k_transpose<<<dim3(4, 4, 40), dim3(32, 8), 0, stream>>>(W_rel, wt_z1, 128, 128,
                                                          4, 8, 4, 4, 4, 0);
  k_transpose<<<dim3(4, 4, 10), dim3(32, 8), 0, stream>>>(W_loop, wt_z0, 128, 128,
                                                          1, 1, 0, 1, 5, 4);
  k_transpose<<<dim3(8, 8, 10), dim3(32, 8), 0, stream>>>(W_u1, wt_u1, 256, 256,
                                                          1, 1, 0, 1, 1, 0);
  k_transpose<<<dim3(4, 12, 10), dim3(32, 8), 0, stream>>>(W_u2, wt_u2, 384, 128,
                                                           1, 1, 0, 1, 1, 0);
  k_cvt<<<(N * 64 / 4 + 255) / 256, 256, 0, stream>>>(feats, featsb, N * 64 / 4);

  // --- dst-CSR build ---
  k_zero<<<128, 256, 0, stream>>>(rowCnt, N);
  k_hist_row<<<(E + 255) / 256, 256, 0, stream>>>(dst, E, rowCnt);
  k_scan_part<<<256, 256, 0, stream>>>(rowCnt, N, thrPre, blkSum);
  k_scan_mid<<<1, 256, 0, stream>>>(blkSum, 256, N, blkOff, rowStart);
  k_scan_fin<<<256, 256, 0, stream>>>(rowCnt, N, thrPre, blkOff, rowStart, rowCur);
  k_place_row<<<(E + 255) / 256, 256, 0, stream>>>(etype, src, dst, rowCur, epk, E);

  const dim3 blk(256);
  const int gm = (N + 127) / 128;
  const dim3 gseg((N + 15) / 16);

  // input projection: x0 = tanh(featsb @ W_in + b_in)
  gemm_lds<64, 64, 2><<<dim3(1, gm), blk, 0, stream>>>(
      featsb, featsb, wt_in, b_in, xb0, nullptr, N, HID, 1);

  for (int l = 0; l < NL; l++) {
    const __bf16* xin = (l & 1) ? xb1 : xb0;
    __bf16* xout = (l & 1) ? xb0 : xb1;

    // pass 0: Z = xin @ [W_0..3 | W_loop]  (N x 640)
    gemm_lds<128, 128, 2><<<dim3(5, gm), blk, 0, stream>>>(
        xin, xin, wt_z0 + (size_t)l * 5 * TS, nullptr, Z, nullptr, N, 640, 0);
    // seg0: msg = b + Z_self + sum(r<4) edges
    seg_sum<<<gseg, blk, 0, stream>>>(Z, rowStart, epk, b_rel + (size_t)l * HID,
                                      msgb, N, 0, 640, 512);
    // pass 1: Z = xin @ [W_4..7]  (N x 512)
    gemm_lds<128, 128, 2><<<dim3(4, gm), blk, 0, stream>>>(
        xin, xin, wt_z1 + (size_t)l * 4 * TS, nullptr, Z, nullptr, N, 512, 0);
    // seg1: msg += sum(r>=4) edges
    seg_sum<<<gseg, blk, 0, stream>>>(Z, rowStart, epk, nullptr,
                                      msgb, N, 4, 512, -1);

    // mid = tanh([x | msg] @ W_u1[l] + b_u1[l])   (mid aliases Z; Z is dead)
    gemm_lds<256, 128, 2><<<dim3(2, gm), blk, 0, stream>>>(
        xin, msgb, wt_u1 + (size_t)l * 256 * 256, b_u1 + (size_t)l * 256,
        mid, nullptr, N, 256, 1);

    // x' = tanh([x | mid] @ W_u2[l] + b_u2[l]); last layer -> f32 d_out
    gemm_lds<384, 128, 2><<<dim3(1, gm), blk, 0, stream>>>(
        xin, mid, wt_u2 + (size_t)l * HID * 384, b_u2 + (size_t)l * HID,
        (l == NL - 1) ? nullptr : xout,
        (l == NL - 1) ? (float*)d_out : nullptr,
        N, HID, 1);
  }
}

// Round 6
// 2648.704 us; speedup vs baseline: 1.1422x; 1.1422x over previous
//
#include <hip/hip_runtime.h>
#include <cstddef>

// ---------------------------------------------------------------------------
// RelGraphConv GNN, 10 layers. Round 14: revert R13 pipeline graft (regressed
//   2665->3025; m141-style order-pinning defeated compiler scheduling), keep
//   the proven R12 DMA-staged GEMM (3.3 TB/s) + grid swap (cols fastest; R13
//   counters showed FETCH == ideal). NEW: fold W_loop into W_u1:
//     [x|msg]@Wu1 = x@(Wu1_top + Wloop@Wu1_bot) + (agg + b_rel)@Wu1_bot
//   -> pass0 Z shrinks 640->512 cols (-25.6 MB write/layer), seg0 drops the
//   self-column read (-25.6 MB/layer). Weight fold done once per launch by
//   k_fold_wu1 (f32 math, one bf16 cast — same rounding profile as before).
// Z buffer (102 MB) aliases mid (dead during Z/segsum); ws ~210 MB.
// N=100000, E=600000, F=64, H=128, R=8.
// ---------------------------------------------------------------------------

#define HID 128
#define NREL 8
#define NL 10

typedef __attribute__((ext_vector_type(8))) __bf16 bf16x8;
typedef __attribute__((ext_vector_type(4))) float f32x4;

__device__ __forceinline__ float fast_tanh(float x) {
  float cx = fminf(fmaxf(x, -10.f), 10.f);
  float z = exp2f(cx * 2.8853900817779268f);
  return (z - 1.f) * __builtin_amdgcn_rcpf(z + 1.f);
}

// --- batched transpose + f32->bf16: tile z: W[zi][K][Nc] -> Wt[zo][Nc][K] ---
__global__ __launch_bounds__(256) void k_transpose(const float* __restrict__ W,
                                                   __bf16* __restrict__ Wt,
                                                   int K, int Nc,
                                                   int inDiv, int inScale, int inOff,
                                                   int outDiv, int outScale, int outOff) {
  __shared__ float t[32][33];
  int z = blockIdx.z;
  int zi = (z / inDiv) * inScale + (z % inDiv) + inOff;
  int zo = (z / outDiv) * outScale + (z % outDiv) + outOff;
  const float* Wz = W + (size_t)zi * K * Nc;
  __bf16* Wtz = Wt + (size_t)zo * K * Nc;
  int n0 = blockIdx.x * 32, k0 = blockIdx.y * 32;
#pragma unroll
  for (int i = 0; i < 4; i++) {
    int k = k0 + threadIdx.y + i * 8;
    int n = n0 + threadIdx.x;
    t[threadIdx.y + i * 8][threadIdx.x] = Wz[(size_t)k * Nc + n];
  }
  __syncthreads();
#pragma unroll
  for (int i = 0; i < 4; i++) {
    int n = n0 + threadIdx.y + i * 8;
    int k = k0 + threadIdx.x;
    Wtz[(size_t)n * K + k] = (__bf16)t[threadIdx.x][threadIdx.y + i * 8];
  }
}

// --- fold W_loop into wt_u1 (k<128 rows): wt[n][k] = Wu1[k][n] + sum_j
//     Wloop[k][j]*Wu1[128+j][n].  Runs AFTER k_transpose(W_u1) (same stream).
__global__ __launch_bounds__(256) void k_fold_wu1(const float* __restrict__ Wu1,
                                                  const float* __restrict__ Wloop,
                                                  __bf16* __restrict__ wt) {
  int l = blockIdx.y;
  int n0 = blockIdx.x * 32;
  const float* wu1 = Wu1 + (size_t)l * 256 * 256;
  const float* wl = Wloop + (size_t)l * 128 * 128;
  __bf16* wtl = wt + (size_t)l * 256 * 256;
  __shared__ float bot[128][33];
  for (int t = threadIdx.x; t < 128 * 32; t += 256) {
    int j = t >> 5, c = t & 31;
    bot[j][c] = wu1[(size_t)(128 + j) * 256 + n0 + c];
  }
  __syncthreads();
  int k = threadIdx.x & 127;
  int half = threadIdx.x >> 7;
  float acc[16];
#pragma unroll
  for (int c = 0; c < 16; c++) acc[c] = 0.f;
  for (int j = 0; j < 128; j++) {
    float w = wl[(size_t)k * 128 + j];
#pragma unroll
    for (int c = 0; c < 16; c++) acc[c] += w * bot[j][half * 16 + c];
  }
#pragma unroll
  for (int c = 0; c < 16; c++) {
    int n = n0 + half * 16 + c;
    wtl[(size_t)n * 256 + k] = (__bf16)(wu1[(size_t)k * 256 + n] + acc[c]);
  }
}

// --- f32 -> bf16 elementwise (n4 = count/4) ---
__global__ __launch_bounds__(256) void k_cvt(const float* __restrict__ x,
                                             __bf16* __restrict__ y, int n4) {
  int i = blockIdx.x * 256 + threadIdx.x;
  if (i < n4) {
    float4 f = ((const float4*)x)[i];
    __bf16 o[4] = {(__bf16)f.x, (__bf16)f.y, (__bf16)f.z, (__bf16)f.w};
    *(uint2*)(y + (size_t)i * 4) = *(uint2*)o;
  }
}

// ===================== dst-CSR build (once per launch) ======================
__global__ __launch_bounds__(256) void k_zero(int* __restrict__ p, int n) {
  for (int i = blockIdx.x * 256 + threadIdx.x; i < n; i += gridDim.x * 256) p[i] = 0;
}

__global__ __launch_bounds__(256) void k_hist_row(const int* __restrict__ dst,
                                                  int E, int* __restrict__ rowCnt) {
  int e = blockIdx.x * 256 + threadIdx.x;
  if (e < E) atomicAdd(&rowCnt[dst[e]], 1);
}

// --- hierarchical prefix scan over rowCnt[0..nb) ---------------------------
__global__ __launch_bounds__(256) void k_scan_part(const int* __restrict__ rowCnt,
                                                   int nb, int* __restrict__ thrPre,
                                                   int* __restrict__ blkSum) {
  __shared__ int sdata[256];
  int tid = threadIdx.x;
  int gtid = blockIdx.x * 256 + tid;
  int tot = gridDim.x * 256;
  int chunk = (nb + tot - 1) / tot;
  int lo = gtid * chunk, hi = min(nb, lo + chunk);
  int s = 0;
  for (int i = lo; i < hi; i++) s += rowCnt[i];
  sdata[tid] = s;
  __syncthreads();
#pragma unroll
  for (int off = 1; off < 256; off <<= 1) {
    int t = (tid >= off) ? sdata[tid - off] : 0;
    __syncthreads();
    sdata[tid] += t;
    __syncthreads();
  }
  thrPre[gtid] = sdata[tid] - s;
  if (tid == 255) blkSum[blockIdx.x] = sdata[255];
}

__global__ __launch_bounds__(256) void k_scan_mid(const int* __restrict__ blkSum,
                                                  int nblk, int nb,
                                                  int* __restrict__ blkOff,
                                                  int* __restrict__ rowStart) {
  __shared__ int part[256];
  int tid = threadIdx.x;
  part[tid] = (tid < nblk) ? blkSum[tid] : 0;
  __syncthreads();
  if (tid == 0) {
    int a = 0;
    for (int i = 0; i < nblk; i++) { int v = part[i]; part[i] = a; a += v; }
    rowStart[nb] = a;
  }
  __syncthreads();
  if (tid < nblk) blkOff[tid] = part[tid];
}

__global__ __launch_bounds__(256) void k_scan_fin(const int* __restrict__ rowCnt,
                                                  int nb,
                                                  const int* __restrict__ thrPre,
                                                  const int* __restrict__ blkOff,
                                                  int* __restrict__ rowStart,
                                                  int* __restrict__ rowCur) {
  int tid = threadIdx.x;
  int gtid = blockIdx.x * 256 + tid;
  int tot = gridDim.x * 256;
  int chunk = (nb + tot - 1) / tot;
  int lo = gtid * chunk, hi = min(nb, lo + chunk);
  int run = blkOff[blockIdx.x] + thrPre[gtid];
  for (int i = lo; i < hi; i++) {
    rowStart[i] = run;
    rowCur[i] = run;
    run += rowCnt[i];
  }
}

// pack: src (17 bits) | etype << 17
__global__ __launch_bounds__(256) void k_place_row(const int* __restrict__ et,
                                                   const int* __restrict__ src,
                                                   const int* __restrict__ dst,
                                                   int* __restrict__ rowCur,
                                                   int* __restrict__ epk, int E) {
  int e = blockIdx.x * 256 + threadIdx.x;
  if (e < E) {
    int p = atomicAdd(&rowCur[dst[e]], 1);
    epk[p] = src[e] | (et[e] << 17);
  }
}

// ========================= CSR segment-sum kernel ===========================
// 16 lanes per dst row. Init: b_rel_l (pass 0) else msgb (pass 1).
__global__ __launch_bounds__(256) void seg_sum(
    const __bf16* __restrict__ Z, const int* __restrict__ rowStart,
    const int* __restrict__ epk, const float* __restrict__ b_rel_l,
    __bf16* __restrict__ msgb, int N, int relBase, int zW) {
  int t16 = threadIdx.x & 15;
  int d = blockIdx.x * 16 + (threadIdx.x >> 4);
  if (d >= N) return;

  float acc[8];
  if (b_rel_l) {
#pragma unroll
    for (int z = 0; z < 8; z++) acc[z] = b_rel_l[t16 * 8 + z];
  } else {
    bf16x8 mv = *(const bf16x8*)(msgb + (size_t)d * HID + t16 * 8);
#pragma unroll
    for (int z = 0; z < 8; z++) acc[z] = (float)mv[z];
  }

  int lo = rowStart[d], hi = rowStart[d + 1];
  for (int e = lo; e < hi; e++) {
    int p = epk[e];
    int rr = (p >> 17) - relBase;
    if ((unsigned)rr < 4u) {
      bf16x8 v = *(const bf16x8*)(Z + (size_t)(p & 0x1FFFF) * zW + rr * HID + t16 * 8);
#pragma unroll
      for (int z = 0; z < 8; z++) acc[z] += (float)v[z];
    }
  }

  bf16x8 o;
#pragma unroll
  for (int z = 0; z < 8; z++) o[z] = (__bf16)acc[z];
  *(bf16x8*)(msgb + (size_t)d * HID + t16 * 8) = o;
}

// ---------------------------------------------------------------------------
// DMA-staged bf16 MFMA GEMM (R12-proven): C = act(concat(A0,A1) @ B + bias)
//   128x128 C-tile, 256 threads, BK=32 double-buffered via global_load_lds,
//   stage(k+1) issued before compute(k), one __syncthreads per step.
//   grid: blockIdx.x = column tile (fastest), blockIdx.y = m tile.
// ---------------------------------------------------------------------------
template <int K, int K0, int MINW>
__global__ __launch_bounds__(256, MINW) void gemm_lds(
    const __bf16* __restrict__ A0, const __bf16* __restrict__ A1,
    const __bf16* __restrict__ Bt, const float* __restrict__ bias,
    __bf16* __restrict__ Cb, float* __restrict__ Cf,
    int M, int Nc, int act) {
  constexpr int NS = K / 32;
  constexpr int NS0 = K0 / 32;
  constexpr int K1 = (K - K0) > 0 ? (K - K0) : 1;
  __shared__ __bf16 As[2][128][32];
  __shared__ __bf16 Bs[2][128][32];

  const int tid = threadIdx.x;
  const int m0 = blockIdx.y * 128;
  const int bn0 = blockIdx.x * 128;
  const int w = tid >> 6;
  const int lane = tid & 63;

  const int cA = w * 128 + lane;
  const int r0 = cA >> 2, s0 = cA & 3;
  const int r1 = (cA + 64) >> 2, s1 = (cA + 64) & 3;

  auto stage_step = [&](int b, int ks) {
    {
      const __bf16* g0 = Bt + (size_t)(bn0 + r0) * K + ks * 32 + s0 * 8;
      __builtin_amdgcn_global_load_lds(
          (const __attribute__((address_space(1))) void*)g0,
          (__attribute__((address_space(3))) void*)(&Bs[b][0][0] + (w * 2 + 0) * 512),
          16, 0, 0);
      const __bf16* g1 = Bt + (size_t)(bn0 + r1) * K + ks * 32 + s1 * 8;
      __builtin_amdgcn_global_load_lds(
          (const __attribute__((address_space(1))) void*)g1,
          (__attribute__((address_space(3))) void*)(&Bs[b][0][0] + (w * 2 + 1) * 512),
          16, 0, 0);
    }
    if (ks < NS0) {
      const __bf16* g0 = A0 + (size_t)(m0 + r0) * K0 + ks * 32 + s0 * 8;
      __builtin_amdgcn_global_load_lds(
          (const __attribute__((address_space(1))) void*)g0,
          (__attribute__((address_space(3))) void*)(&As[b][0][0] + (w * 2 + 0) * 512),
          16, 0, 0);
      const __bf16* g1 = A0 + (size_t)(m0 + r1) * K0 + ks * 32 + s1 * 8;
      __builtin_amdgcn_global_load_lds(
          (const __attribute__((address_space(1))) void*)g1,
          (__attribute__((address_space(3))) void*)(&As[b][0][0] + (w * 2 + 1) * 512),
          16, 0, 0);
    } else {
      const __bf16* g0 = A1 + (size_t)(m0 + r0) * K1 + (ks - NS0) * 32 + s0 * 8;
      __builtin_amdgcn_global_load_lds(
          (const __attribute__((address_space(1))) void*)g0,
          (__attribute__((address_space(3))) void*)(&As[b][0][0] + (w * 2 + 0) * 512),
          16, 0, 0);
      const __bf16* g1 = A1 + (size_t)(m0 + r1) * K1 + (ks - NS0) * 32 + s1 * 8;
      __builtin_amdgcn_global_load_lds(
          (const __attribute__((address_space(1))) void*)g1,
          (__attribute__((address_space(3))) void*)(&As[b][0][0] + (w * 2 + 1) * 512),
          16, 0, 0);
    }
  };

  const int ml = lane & 15, q = lane >> 4;
  const int wr = (w >> 1) * 64, wc = (w & 1) * 64;

  f32x4 acc[4][4];
#pragma unroll
  for (int i = 0; i < 4; i++)
#pragma unroll
    for (int j = 0; j < 4; j++)
#pragma unroll
      for (int r = 0; r < 4; r++) acc[i][j][r] = 0.f;

  stage_step(0, 0);
  __syncthreads();  // implicit vmcnt(0): buffer 0 ready

#pragma unroll
  for (int ks = 0; ks < NS; ks++) {
    const int cur = ks & 1;
    if (ks + 1 < NS) stage_step(cur ^ 1, ks + 1);  // async DMA, in flight
    bf16x8 af[4], bfr[4];
#pragma unroll
    for (int i = 0; i < 4; i++)
      af[i] = *(const bf16x8*)(&As[cur][wr + i * 16 + ml][q * 8]);
#pragma unroll
    for (int j = 0; j < 4; j++)
      bfr[j] = *(const bf16x8*)(&Bs[cur][wc + j * 16 + ml][q * 8]);
#pragma unroll
    for (int i = 0; i < 4; i++)
#pragma unroll
      for (int j = 0; j < 4; j++)
        acc[i][j] = __builtin_amdgcn_mfma_f32_16x16x32_bf16(af[i], bfr[j],
                                                            acc[i][j], 0, 0, 0);
    __syncthreads();  // drains stage(ks+1) DMA; protects buf reuse
  }

  // --- epilogue ---
#pragma unroll
  for (int i = 0; i < 4; i++) {
#pragma unroll
    for (int r = 0; r < 4; r++) {
      int grow = m0 + wr + i * 16 + q * 4 + r;
      if (grow >= M) continue;
#pragma unroll
      for (int j = 0; j < 4; j++) {
        int col = bn0 + wc + j * 16 + ml;
        float v = acc[i][j][r];
        if (bias) v += bias[col];
        if (act) v = fast_tanh(v);
        if (Cb) Cb[(size_t)grow * Nc + col] = (__bf16)v;
        if (Cf) Cf[(size_t)grow * Nc + col] = v;
      }
    }
  }
}

extern "C" void kernel_launch(void* const* d_in, const int* in_sizes, int n_in,
                              void* d_out, int out_size, void* d_ws, size_t ws_size,
                              hipStream_t stream) {
  const float* feats  = (const float*)d_in[0];
  const int*   src    = (const int*)d_in[1];
  const int*   dst    = (const int*)d_in[2];
  const int*   etype  = (const int*)d_in[3];
  const float* W_in   = (const float*)d_in[4];
  const float* b_in   = (const float*)d_in[5];
  const float* W_rel  = (const float*)d_in[6];
  const float* W_loop = (const float*)d_in[7];
  const float* b_rel  = (const float*)d_in[8];
  const float* W_u1   = (const float*)d_in[9];
  const float* b_u1   = (const float*)d_in[10];
  const float* W_u2   = (const float*)d_in[11];
  const float* b_u2   = (const float*)d_in[12];

  const int E = in_sizes[1];
  const int N = in_sizes[0] / 64;
  const int TS = HID * HID;

  // --- workspace layout (~210 MB) ---
  __bf16* xb0  = (__bf16*)d_ws;                       // N*128
  __bf16* xb1  = xb0 + (size_t)N * HID;               // N*128
  __bf16* msgb = xb1 + (size_t)N * HID;               // N*128
  __bf16* U    = msgb + (size_t)N * HID;              // N*640 (Z | mid | featsb)
  __bf16* Z    = U;
  __bf16* mid  = U;
  __bf16* featsb = U;
  __bf16* wt_in = U + (size_t)N * 640;                // [128][64]
  __bf16* wt_z0 = wt_in + 128 * 64;                   // [10][4][128][128]
  __bf16* wt_z1 = wt_z0 + (size_t)10 * 4 * TS;        // [10][4][128][128]
  __bf16* wt_u1 = wt_z1 + (size_t)10 * 4 * TS;        // [10][256][256]
  __bf16* wt_u2 = wt_u1 + (size_t)10 * 256 * 256;     // [10][128][384]
  int* rowCnt   = (int*)(wt_u2 + (size_t)10 * 128 * 384); // N
  int* rowStart = rowCnt + N;                         // N+1
  int* rowCur   = rowStart + N + 1;                   // N
  int* epk      = rowCur + N;                         // E
  int* thrPre   = epk + E;                            // 256*256
  int* blkSum   = thrPre + 256 * 256;                 // 256
  int* blkOff   = blkSum + 256;                       // 256

  // --- weight transpose+convert ---
  k_transpose<<<dim3(4, 2, 1), dim3(32, 8), 0, stream>>>(W_in, wt_in, 64, 128,
                                                         1, 1, 0, 1, 1, 0);
  // W_rel r<4 -> wt_z0 tiles (l*4 + r)
  k_transpose<<<dim3(4, 4, 40), dim3(32, 8), 0, stream>>>(W_rel, wt_z0, 128, 128,
                                                          4, 8, 0, 4, 4, 0);
  // W_rel r>=4 -> wt_z1 tiles (l*4 + r-4)
  k_transpose<<<dim3(4, 4, 40), dim3(32, 8), 0, stream>>>(W_rel, wt_z1, 128, 128,
                                                          4, 8, 4, 4, 4, 0);
  // W_u1, W_u2
  k_transpose<<<dim3(8, 8, 10), dim3(32, 8), 0, stream>>>(W_u1, wt_u1, 256, 256,
                                                          1, 1, 0, 1, 1, 0);
  // fold W_loop into wt_u1 rows k<128 (after transpose; same stream)
  k_fold_wu1<<<dim3(8, 10), dim3(256), 0, stream>>>(W_u1, W_loop, wt_u1);
  k_transpose<<<dim3(4, 12, 10), dim3(32, 8), 0, stream>>>(W_u2, wt_u2, 384, 128,
                                                           1, 1, 0, 1, 1, 0);
  k_cvt<<<(N * 64 / 4 + 255) / 256, 256, 0, stream>>>(feats, featsb, N * 64 / 4);

  // --- dst-CSR build ---
  k_zero<<<128, 256, 0, stream>>>(rowCnt, N);
  k_hist_row<<<(E + 255) / 256, 256, 0, stream>>>(dst, E, rowCnt);
  k_scan_part<<<256, 256, 0, stream>>>(rowCnt, N, thrPre, blkSum);
  k_scan_mid<<<1, 256, 0, stream>>>(blkSum, 256, N, blkOff, rowStart);
  k_scan_fin<<<256, 256, 0, stream>>>(rowCnt, N, thrPre, blkOff, rowStart, rowCur);
  k_place_row<<<(E + 255) / 256, 256, 0, stream>>>(etype, src, dst, rowCur, epk, E);

  const dim3 blk(256);
  const int gm = (N + 127) / 128;
  const dim3 gseg((N + 15) / 16);

  // input projection: x0 = tanh(featsb @ W_in + b_in)
  gemm_lds<64, 64, 2><<<dim3(1, gm), blk, 0, stream>>>(
      featsb, featsb, wt_in, b_in, xb0, nullptr, N, HID, 1);

  for (int l = 0; l < NL; l++) {
    const __bf16* xin = (l & 1) ? xb1 : xb0;
    __bf16* xout = (l & 1) ? xb0 : xb1;

    // pass 0: Z = xin @ [W_0..3]  (N x 512; W_loop folded into wt_u1)
    gemm_lds<128, 128, 2><<<dim3(4, gm), blk, 0, stream>>>(
        xin, xin, wt_z0 + (size_t)l * 4 * TS, nullptr, Z, nullptr, N, 512, 0);
    // seg0: msg = b_rel + sum(r<4) edges
    seg_sum<<<gseg, blk, 0, stream>>>(Z, rowStart, epk, b_rel + (size_t)l * HID,
                                      msgb, N, 0, 512);
    // pass 1: Z = xin @ [W_4..7]  (N x 512)
    gemm_lds<128, 128, 2><<<dim3(4, gm), blk, 0, stream>>>(
        xin, xin, wt_z1 + (size_t)l * 4 * TS, nullptr, Z, nullptr, N, 512, 0);
    // seg1: msg += sum(r>=4) edges
    seg_sum<<<gseg, blk, 0, stream>>>(Z, rowStart, epk, nullptr,
                                      msgb, N, 4, 512);

    // mid = tanh([x | msg] @ Wu1_eff[l] + b_u1[l])   (mid aliases Z)
    gemm_lds<256, 128, 2><<<dim3(2, gm), blk, 0, stream>>>(
        xin, msgb, wt_u1 + (size_t)l * 256 * 256, b_u1 + (size_t)l * 256,
        mid, nullptr, N, 256, 1);

    // x' = tanh([x | mid] @ W_u2[l] + b_u2[l]); last layer -> f32 d_out
    gemm_lds<384, 128, 2><<<dim3(1, gm), blk, 0, stream>>>(
        xin, mid, wt_u2 + (size_t)l * HID * 384, b_u2 + (size_t)l * HID,
        (l == NL - 1) ? nullptr : xout,
        (l == NL - 1) ? (float*)d_out : nullptr,
        N, HID, 1);
  }
}